// Round 9
// baseline (96.339 us; speedup 1.0000x reference)
//
#include <hip/hip_runtime.h>

// LIF scan: per neuron i, over t: m = beta*m + x[t,i]; s = (m>=thr);
// spikes[t,i]=s; membranes[t,i]=m; m -= thr*s.
// x: (T, B*N) f32. d_out = [spikes | membranes] f32.
//
// R1: float4, plain ld/st:            95.3us
// R2: float4, nt ld + nt st:          87.9us
// R3: float2, nt ld + nt st:          93.2us (more TLP hurt)
// R4: float4, caching ld + nt st:     74.8us
// R5: +depth-3 rotating prefetch:     74.8us (MLP not the wall)
// R6: ILP-2,  512 wgs,  8KB/stream/t: 67.3us (5.97 TB/s)
// R7: ILP-4,  256 wgs, 16KB/stream/t: 63.2us (6.36 TB/s)
// R8: ILP-8,  128 wgs, 32KB/stream/t: 60.8us (6.61 TB/s) — burst widening
//     keeps paying, diminishing (+7.5/+4.1/+2.4us per doubling).
// R9: ILP-16, 64 wgs, 64KB contiguous per stream per t, ~192 streams.
//     Target 58.5-60us; flat/worse => R8 is the roofline (~6.6 TB/s eff,
//     94% of the 57.4us pure-fill-rate bound).

typedef float f32x4 __attribute__((ext_vector_type(4)));

#define LIF_BETA 0.25f
#define LIF_THR  1.0f
#define LIF_T    32
#define ILP      16

__global__ __launch_bounds__(256) void lif_scan_kernel(
    const f32x4* __restrict__ x,
    f32x4* __restrict__ spikes,
    f32x4* __restrict__ membranes,
    int bn4)  // (B*N)/4
{
    // Each workgroup owns a 4096-wide contiguous chunk of float4 columns.
    int base = blockIdx.x * (ILP * 256) + threadIdx.x;
    if (base + (ILP - 1) * 256 >= bn4) {
        if (base >= bn4) return;  // safety; exact fit for bn4=262144, 64 wgs
    }

    f32x4 m[ILP];
#pragma unroll
    for (int c = 0; c < ILP; ++c) m[c] = (f32x4){0.f, 0.f, 0.f, 0.f};

#pragma unroll
    for (int t = 0; t < LIF_T; ++t) {
        size_t rowoff = (size_t)t * (size_t)bn4;

        f32x4 xv[ILP];
#pragma unroll
        for (int c = 0; c < ILP; ++c)
            xv[c] = x[rowoff + base + (size_t)(c * 256)];  // caching loads

        f32x4 s[ILP];
#pragma unroll
        for (int c = 0; c < ILP; ++c) {
            m[c].x = LIF_BETA * m[c].x + xv[c].x;
            m[c].y = LIF_BETA * m[c].y + xv[c].y;
            m[c].z = LIF_BETA * m[c].z + xv[c].z;
            m[c].w = LIF_BETA * m[c].w + xv[c].w;
            s[c].x = (m[c].x >= LIF_THR) ? 1.0f : 0.0f;
            s[c].y = (m[c].y >= LIF_THR) ? 1.0f : 0.0f;
            s[c].z = (m[c].z >= LIF_THR) ? 1.0f : 0.0f;
            s[c].w = (m[c].w >= LIF_THR) ? 1.0f : 0.0f;
        }

        // NT stores, grouped by output array for max per-array burst width
#pragma unroll
        for (int c = 0; c < ILP; ++c)
            __builtin_nontemporal_store(s[c], &spikes[rowoff + base + (size_t)(c * 256)]);
#pragma unroll
        for (int c = 0; c < ILP; ++c)
            __builtin_nontemporal_store(m[c], &membranes[rowoff + base + (size_t)(c * 256)]);

#pragma unroll
        for (int c = 0; c < ILP; ++c) {
            m[c].x -= LIF_THR * s[c].x;
            m[c].y -= LIF_THR * s[c].y;
            m[c].z -= LIF_THR * s[c].z;
            m[c].w -= LIF_THR * s[c].w;
        }
    }
}

extern "C" void kernel_launch(void* const* d_in, const int* in_sizes, int n_in,
                              void* d_out, int out_size, void* d_ws, size_t ws_size,
                              hipStream_t stream) {
    (void)n_in; (void)d_ws; (void)ws_size;

    const float* x = (const float*)d_in[0];
    float* out = (float*)d_out;

    const int total = in_sizes[0];          // T * B * N
    const int bn = total / LIF_T;           // B * N = 1,048,576
    const int bn4 = bn / 4;                 // 262,144

    float* spikes = out;                    // first T*B*N floats
    float* membranes = out + (size_t)total; // second T*B*N floats

    const int block = 256;
    const int grid = bn4 / (ILP * 256);     // 64 blocks, 16 float4/thread

    lif_scan_kernel<<<grid, block, 0, stream>>>(
        (const f32x4*)x, (f32x4*)spikes, (f32x4*)membranes, bn4);
}

// Round 10
// 61.083 us; speedup vs baseline: 1.5772x; 1.5772x over previous
//
#include <hip/hip_runtime.h>

// LIF scan: per neuron i, over t: m = beta*m + x[t,i]; s = (m>=thr);
// spikes[t,i]=s; membranes[t,i]=m; m -= thr*s.
// x: (T, B*N) f32. d_out = [spikes | membranes] f32.
//
// R1: float4, plain ld/st:            95.3us
// R2: float4, nt ld + nt st:          87.9us
// R3: float2, nt ld + nt st:          93.2us (more TLP hurt)
// R4: float4, caching ld + nt st:     74.8us
// R5: +depth-3 rotating prefetch:     74.8us (MLP not the wall)
// R6: ILP-2,  512 wgs,  8KB/stream/t: 67.3us (5.97 TB/s)
// R7: ILP-4,  256 wgs, 16KB/stream/t: 63.2us (6.36 TB/s)
// R8: ILP-8,  128 wgs, 32KB/stream/t: 60.8us (6.61 TB/s)  <== best
// R9: ILP-16, 64 wgs:                 96.3us — VGPR_Count=80 proves the
//     compiler serialized the 16-load batch into register-reuse groups
//     (needs ~192 VGPRs); 64 wgs also idles 3/4 of the CUs. Burst-widening
//     curve: +7.5/+4.1/+2.4us then collapse => R8 is the knee.
//     R9 FETCH=66MB (<134MB mandatory) confirms x is partially L3-resident;
//     writes (268MB) dominate. 6.61 TB/s eff is above the copy ceiling
//     (6.29) and 94% of the pure-fill bound (57.4us) => at the mixed-stream
//     DRAM roofline. REVERT to R8 verbatim.

typedef float f32x4 __attribute__((ext_vector_type(4)));

#define LIF_BETA 0.25f
#define LIF_THR  1.0f
#define LIF_T    32

__global__ __launch_bounds__(256) void lif_scan_kernel(
    const f32x4* __restrict__ x,
    f32x4* __restrict__ spikes,
    f32x4* __restrict__ membranes,
    int bn4)  // (B*N)/4
{
    // Each workgroup owns a 2048-wide contiguous chunk of float4 columns.
    int base = blockIdx.x * 2048 + threadIdx.x;
    if (base + 1792 >= bn4) {
        if (base >= bn4) return;  // safety; exact fit for bn4=262144, 128 wgs
    }

    f32x4 m[8];
#pragma unroll
    for (int c = 0; c < 8; ++c) m[c] = (f32x4){0.f, 0.f, 0.f, 0.f};

#pragma unroll
    for (int t = 0; t < LIF_T; ++t) {
        size_t rowoff = (size_t)t * (size_t)bn4;

        f32x4 xv[8];
#pragma unroll
        for (int c = 0; c < 8; ++c)
            xv[c] = x[rowoff + base + (size_t)(c * 256)];  // caching loads

        f32x4 s[8];
#pragma unroll
        for (int c = 0; c < 8; ++c) {
            m[c].x = LIF_BETA * m[c].x + xv[c].x;
            m[c].y = LIF_BETA * m[c].y + xv[c].y;
            m[c].z = LIF_BETA * m[c].z + xv[c].z;
            m[c].w = LIF_BETA * m[c].w + xv[c].w;
            s[c].x = (m[c].x >= LIF_THR) ? 1.0f : 0.0f;
            s[c].y = (m[c].y >= LIF_THR) ? 1.0f : 0.0f;
            s[c].z = (m[c].z >= LIF_THR) ? 1.0f : 0.0f;
            s[c].w = (m[c].w >= LIF_THR) ? 1.0f : 0.0f;
        }

        // NT stores, grouped by output array for max per-array burst width
#pragma unroll
        for (int c = 0; c < 8; ++c)
            __builtin_nontemporal_store(s[c], &spikes[rowoff + base + (size_t)(c * 256)]);
#pragma unroll
        for (int c = 0; c < 8; ++c)
            __builtin_nontemporal_store(m[c], &membranes[rowoff + base + (size_t)(c * 256)]);

#pragma unroll
        for (int c = 0; c < 8; ++c) {
            m[c].x -= LIF_THR * s[c].x;
            m[c].y -= LIF_THR * s[c].y;
            m[c].z -= LIF_THR * s[c].z;
            m[c].w -= LIF_THR * s[c].w;
        }
    }
}

extern "C" void kernel_launch(void* const* d_in, const int* in_sizes, int n_in,
                              void* d_out, int out_size, void* d_ws, size_t ws_size,
                              hipStream_t stream) {
    (void)n_in; (void)d_ws; (void)ws_size;

    const float* x = (const float*)d_in[0];
    float* out = (float*)d_out;

    const int total = in_sizes[0];          // T * B * N
    const int bn = total / LIF_T;           // B * N = 1,048,576
    const int bn4 = bn / 4;                 // 262,144

    float* spikes = out;                    // first T*B*N floats
    float* membranes = out + (size_t)total; // second T*B*N floats

    const int block = 256;
    const int grid = bn4 / 2048;            // 128 blocks, 8 float4/thread

    lif_scan_kernel<<<grid, block, 0, stream>>>(
        (const f32x4*)x, (f32x4*)spikes, (f32x4*)membranes, bn4);
}